// Round 11
// baseline (300.392 us; speedup 1.0000x reference)
//
#include <hip/hip_runtime.h>

#define NJ 24
#define NV 6890
#define NB 1024
#define NRQ 218       // 1 + 10 betas + 207 pose
#define QPAD 224
#define MM 600        // 576 (jj,j) pairs + 24 plain-Jr rows
#define NCOLR 654     // real data columns (218*3)
#define NCOL 655      // + ones column at 654
#define DPAD 704      // D row stride (covers 11 x 64 n-tiles)
#define EDIM 1728     // 576*3
#define KCH 862       // vertices per split-K chunk (8 x 862 = 6896 >= 6890)
#define MROWS 640     // P m-rows (5 x 128 tiles)
#define PSLAB (MROWS * DPAD)   // 450,560 floats per z-slab

// ---- workspace layout (bytes), total 40,650,112 (validated guard) ----
constexpr size_t OFF_P  = 0;                       // P  f32 [8][640][704] 14,417,920
constexpr size_t OFF_M  = 0;                       // M  f32 [NB][EDIM]     7,077,888 (aliases P; P dead by then)
constexpr size_t OFF_D  = 17638400;                // D  f32 [NV][DPAD]    19,402,240
constexpr size_t OFF_KQ = 37040640;                // KQ f32 [NRQ][EDIM]    1,506,816
constexpr size_t OFF_W  = 38547456;                // W  f32 [576]              2,304
constexpr size_t OFF_JQ = 38549760;                // JQ f32 [11][72]           3,200
constexpr size_t OFF_Q  = 38552960;                // qT f32 [QPAD][NB]       917,504
constexpr size_t OFF_A  = 39470464;                // A  f32 [NB][288]      1,179,648
constexpr size_t TOTAL_WS = 40650112;

// =================== fast path kernels ===================

// D[v][n] = src_r[v*3+c] (n=r*3+c<654), 1.0 (n==654), 0 pad
__global__ __launch_bounds__(256) void k_dfill(const float* __restrict__ vt,
                                               const float* __restrict__ sd,
                                               const float* __restrict__ pd,
                                               float* __restrict__ D) {
  const int idx = blockIdx.x * 256 + threadIdx.x;
  const int e0 = idx * 4;
  if (e0 >= NV * DPAD) return;
  const int v = e0 / DPAD;
  const int n0 = e0 - v * DPAD;
  float4 r;
  float* pr = (float*)&r;
  #pragma unroll
  for (int u = 0; u < 4; ++u) {
    const int n = n0 + u;
    float val = 0.f;
    if (n < NCOLR) {
      const int rr = n / 3, c = n - 3 * rr;
      const float* src = (rr == 0) ? vt
                       : (rr <= 10) ? (sd + (size_t)(rr - 1) * (NV * 3))
                                    : (pd + (size_t)(rr - 11) * (NV * 3));
      val = src[v * 3 + c];
    } else if (n == NCOLR) {
      val = 1.0f;
    }
    pr[u] = val;
  }
  *(float4*)&D[(size_t)v * DPAD + n0] = r;
}

// P[z][m][n] = sum_{v in chunk z} G[v][m]*D[v][n], G on the fly (vectorized),
// 128x64 tile, 8x4 acc, split-K=8, DOUBLE-BUFFERED LDS (1 barrier/k-step),
// plain float4 stores (no atomics).
__global__ __launch_bounds__(256) void k_gemm1(const float* __restrict__ Jr,
                                               const float* __restrict__ wts,
                                               const float* __restrict__ D,
                                               float* __restrict__ P) {
  __shared__ float As[2][16][128];
  __shared__ float Bs[2][16][64];
  const int t = threadIdx.x;
  const int n0 = blockIdx.x * 64;
  const int m0 = blockIdx.y * 128;
  const int z  = blockIdx.z;
  const int kbeg = z * KCH;
  const int kend = min(NV, kbeg + KCH);
  const int tm = (t & 15) * 4;        // compute: m offset (+64 for 2nd half)
  const int tn = (t >> 4) * 4;        // compute: n offset
  const int skk = t >> 4;             // staging: k row (vertex offset)
  const int msub = (t & 15) * 8;      // staging: 8 A-columns owned (8-aligned)
  const int scB = (t & 15) * 4;       // staging: 4 B-columns owned

  const int mg = m0 + msub;           // multiple of 8
  int mcase, jjj, j0;
  if (mg < 576)     { mcase = 0; const int g = mg >> 3; jjj = g / 3; j0 = (g - 3 * (g / 3)) * 8; }
  else if (mg < MM) { mcase = 1; jjj = 0; j0 = mg - 576; }
  else              { mcase = 2; jjj = 0; j0 = 0; }

  float4 x0, x1, bv4;
  auto stage = [&](int k0) {
    const int v = k0 + skk;
    x0 = make_float4(0.f, 0.f, 0.f, 0.f);
    x1 = x0; bv4 = x0;
    if (v < kend) {
      const float* __restrict__ jrow = Jr + (size_t)v * NJ;
      if (mcase == 0) {
        const float jv = jrow[jjj];
        const float* __restrict__ wrow = wts + (size_t)v * NJ + j0;
        const float4 w0 = *(const float4*)wrow;
        const float4 w1 = *(const float4*)(wrow + 4);
        x0 = make_float4(jv * w0.x, jv * w0.y, jv * w0.z, jv * w0.w);
        x1 = make_float4(jv * w1.x, jv * w1.y, jv * w1.z, jv * w1.w);
      } else if (mcase == 1) {
        x0 = *(const float4*)(jrow + j0);
        x1 = *(const float4*)(jrow + j0 + 4);
      }
      bv4 = *(const float4*)(D + (size_t)v * DPAD + n0 + scB);
    }
  };

  const int nsteps = (kend - kbeg + 15) >> 4;

  stage(kbeg);
  *(float4*)&As[0][skk][msub]     = x0;
  *(float4*)&As[0][skk][msub + 4] = x1;
  *(float4*)&Bs[0][skk][scB]      = bv4;
  __syncthreads();

  float acc[2][4][4] = {};
  for (int s = 0; s < nsteps; ++s) {
    const int cb = s & 1;
    const bool more = (s + 1 < nsteps);
    if (more) stage(kbeg + (s + 1) * 16);   // prefetch next into regs
    #pragma unroll
    for (int kk = 0; kk < 16; ++kk) {
      float4 a0 = *(const float4*)&As[cb][kk][tm];
      float4 a1 = *(const float4*)&As[cb][kk][tm + 64];
      float4 bv = *(const float4*)&Bs[cb][kk][tn];
      const float a0a[4] = {a0.x, a0.y, a0.z, a0.w};
      const float a1a[4] = {a1.x, a1.y, a1.z, a1.w};
      const float bb[4]  = {bv.x, bv.y, bv.z, bv.w};
      #pragma unroll
      for (int i = 0; i < 4; ++i)
        #pragma unroll
        for (int j = 0; j < 4; ++j) {
          acc[0][i][j] += a0a[i] * bb[j];
          acc[1][i][j] += a1a[i] * bb[j];
        }
    }
    if (more) {
      const int nb = cb ^ 1;
      *(float4*)&As[nb][skk][msub]     = x0;
      *(float4*)&As[nb][skk][msub + 4] = x1;
      *(float4*)&Bs[nb][skk][scB]      = bv4;
      __syncthreads();
    }
  }

  float* __restrict__ Pz = P + (size_t)z * PSLAB;
  #pragma unroll
  for (int h = 0; h < 2; ++h)
    #pragma unroll
    for (int i = 0; i < 4; ++i) {
      const float4 st = make_float4(acc[h][i][0], acc[h][i][1], acc[h][i][2], acc[h][i][3]);
      *(float4*)&Pz[(size_t)(m0 + h * 64 + tm + i) * DPAD + n0 + tn] = st;
    }
}

// sum the 8 split-K partials and scatter into KQ / W / JQ
__global__ __launch_bounds__(256) void k_reduce(const float* __restrict__ P,
                                                float* __restrict__ KQ,
                                                float* __restrict__ W,
                                                float* __restrict__ JQ) {
  const int m = blockIdx.x;           // 0..599
  for (int n = threadIdx.x; n < NCOL; n += 256) {
    float s = 0.f;
    #pragma unroll
    for (int zz = 0; zz < 8; ++zz)
      s += P[(size_t)zz * PSLAB + (size_t)m * DPAD + n];
    if (m < 576) {
      if (n == NCOLR) W[m] = s;
      else { const int rr = n / 3, c = n - 3 * rr; KQ[(size_t)rr * EDIM + m * 3 + c] = s; }
    } else if (n < 33) {
      const int rr = n / 3, c = n - 3 * rr;
      JQ[rr * 72 + (m - 576) * 3 + c] = s;
    }
  }
}

// per-batch Rodrigues + chain -> A[b][288], qT[r][b] (transposed for k_mgemm)
__global__ __launch_bounds__(64) void k_chain(const float* __restrict__ beta,
                                              const float* __restrict__ theta,
                                              const float* __restrict__ JQ,
                                              float* __restrict__ qT,
                                              float* __restrict__ A) {
  const int b = blockIdx.x;
  const int t = threadIdx.x;
  __shared__ float RES[24][12];
  __shared__ float Jl[24][3];
  const int par[24] = {-1,0,0,0,1,2,3,4,5,6,7,8,9,9,9,12,13,14,16,17,18,19,20,21};
  const int dep[24] = {0,1,1,1,2,2,2,3,3,3,4,4,4,4,4,5,5,5,6,6,7,7,8,8};
  float R[9];
  float Jv[3];
  if (t < 6) qT[(size_t)(NRQ + t) * NB + b] = 0.f;   // zero pad rows 218..223
  if (t < NJ) {
    const int j = t;
    const float th0 = theta[b * 72 + j * 3 + 0];
    const float th1 = theta[b * 72 + j * 3 + 1];
    const float th2 = theta[b * 72 + j * 3 + 2];
    const float a0 = th0 + 1e-8f, a1 = th1 + 1e-8f, a2 = th2 + 1e-8f;
    const float angle = sqrtf(a0 * a0 + a1 * a1 + a2 * a2);
    const float inv = 1.0f / angle;
    const float half = 0.5f * angle;
    const float cw = cosf(half), sv = sinf(half);
    float qw = cw, qx = sv * th0 * inv, qy = sv * th1 * inv, qz = sv * th2 * inv;
    const float qn = 1.0f / sqrtf(qw * qw + qx * qx + qy * qy + qz * qz);
    qw *= qn; qx *= qn; qy *= qn; qz *= qn;
    const float w2 = qw * qw, x2 = qx * qx, y2 = qy * qy, z2 = qz * qz;
    const float wx = qw * qx, wy = qw * qy, wz = qw * qz;
    const float xy = qx * qy, xz = qx * qz, yz = qy * qz;
    R[0] = w2 + x2 - y2 - z2; R[1] = 2.f * (xy - wz);   R[2] = 2.f * (xz + wy);
    R[3] = 2.f * (xy + wz);   R[4] = w2 - x2 + y2 - z2; R[5] = 2.f * (yz - wx);
    R[6] = 2.f * (xz - wy);   R[7] = 2.f * (yz + wx);   R[8] = w2 - x2 - y2 + z2;
    float betaf[10];
    #pragma unroll
    for (int s = 0; s < 10; ++s) betaf[s] = beta[b * 10 + s];
    #pragma unroll
    for (int c = 0; c < 3; ++c) {
      float jv = JQ[j * 3 + c];
      #pragma unroll
      for (int s = 0; s < 10; ++s) jv += betaf[s] * JQ[(1 + s) * 72 + j * 3 + c];
      Jv[c] = jv; Jl[j][c] = jv;
    }
    if (j >= 1) {
      #pragma unroll
      for (int k = 0; k < 9; ++k)
        qT[(size_t)(11 + (j - 1) * 9 + k) * NB + b] = R[k] - ((k == 0 || k == 4 || k == 8) ? 1.f : 0.f);
    }
    if (j == 0) qT[b] = 1.f;
    if (j < 10) qT[(size_t)(1 + j) * NB + b] = betaf[j];
  }
  __syncthreads();
  for (int lvl = 0; lvl < 9; ++lvl) {
    if (t < NJ && dep[t] == lvl) {
      if (t == 0) {
        #pragma unroll
        for (int i = 0; i < 3; ++i) {
          RES[0][i * 4 + 0] = R[i * 3 + 0]; RES[0][i * 4 + 1] = R[i * 3 + 1];
          RES[0][i * 4 + 2] = R[i * 3 + 2]; RES[0][i * 4 + 3] = Jv[i];
        }
      } else {
        const int p = par[t];
        const float tr0 = Jv[0] - Jl[p][0];
        const float tr1 = Jv[1] - Jl[p][1];
        const float tr2 = Jv[2] - Jl[p][2];
        float Pr[12];
        #pragma unroll
        for (int k = 0; k < 12; ++k) Pr[k] = RES[p][k];
        #pragma unroll
        for (int i = 0; i < 3; ++i) {
          const float r0 = Pr[i*4+0], r1 = Pr[i*4+1], r2 = Pr[i*4+2], r3 = Pr[i*4+3];
          RES[t][i * 4 + 0] = r0 * R[0] + r1 * R[3] + r2 * R[6];
          RES[t][i * 4 + 1] = r0 * R[1] + r1 * R[4] + r2 * R[7];
          RES[t][i * 4 + 2] = r0 * R[2] + r1 * R[5] + r2 * R[8];
          RES[t][i * 4 + 3] = r0 * tr0 + r1 * tr1 + r2 * tr2 + r3;
        }
      }
    }
    __syncthreads();
  }
  if (t < NJ) {
    float* Ab = A + (size_t)b * 288 + t * 12;
    #pragma unroll
    for (int i = 0; i < 3; ++i) {
      const float r0 = RES[t][i*4+0], r1 = RES[t][i*4+1], r2 = RES[t][i*4+2];
      const float ti = RES[t][i*4+3] - (r0 * Jv[0] + r1 * Jv[1] + r2 * Jv[2]);
      Ab[i*4+0] = r0; Ab[i*4+1] = r1; Ab[i*4+2] = r2; Ab[i*4+3] = ti;
    }
  }
}

// M[b][e] = sum_r qT[r][b] * KQ[r][e]; 64(b) x 64(e) tile, 4x4 acc, K=224
__global__ __launch_bounds__(256) void k_mgemm(const float* __restrict__ qT,
                                               const float* __restrict__ KQ,
                                               float* __restrict__ M) {
  __shared__ float Qs[16][64];
  __shared__ float Ks[16][64];
  const int t = threadIdx.x;
  const int e0 = blockIdx.x * 64;
  const int b0 = blockIdx.y * 64;
  const int tb = (t & 15) * 4;
  const int te = (t >> 4) * 4;
  const int skk = t >> 4;
  const int sc  = (t & 15) * 4;
  float acc[4][4] = {};
  for (int k0 = 0; k0 < QPAD; k0 += 16) {
    const int k = k0 + skk;
    *(float4*)&Qs[skk][sc] = *(const float4*)&qT[(size_t)k * NB + b0 + sc];
    if (k < NRQ) *(float4*)&Ks[skk][sc] = *(const float4*)&KQ[(size_t)k * EDIM + e0 + sc];
    else         *(float4*)&Ks[skk][sc] = make_float4(0.f, 0.f, 0.f, 0.f);
    __syncthreads();
    #pragma unroll
    for (int kk = 0; kk < 16; ++kk) {
      float4 qv = *(const float4*)&Qs[kk][tb];
      float4 kv = *(const float4*)&Ks[kk][te];
      const float qa[4] = {qv.x, qv.y, qv.z, qv.w};
      const float ka[4] = {kv.x, kv.y, kv.z, kv.w};
      #pragma unroll
      for (int i = 0; i < 4; ++i)
        #pragma unroll
        for (int j = 0; j < 4; ++j)
          acc[i][j] += qa[i] * ka[j];
    }
    __syncthreads();
  }
  #pragma unroll
  for (int i = 0; i < 4; ++i) {
    float4 st = make_float4(acc[i][0], acc[i][1], acc[i][2], acc[i][3]);
    *(float4*)&M[(size_t)(b0 + tb + i) * EDIM + e0 + te] = st;
  }
}

// joints[b,jj,i] = sum_j( A[b,j,i,:3] . M[b,(jj,j)*3..] + A[b,j,i,3]*W[jj,j] )
// one batch per block: 10.4 KB LDS, 1024 blocks
__global__ __launch_bounds__(256) void k_joints(const float* __restrict__ M,
                                                const float* __restrict__ A,
                                                const float* __restrict__ W,
                                                float* __restrict__ out) {
  const int b = blockIdx.x;
  const int t = threadIdx.x;
  __shared__ float Ml[EDIM];
  __shared__ float Al[288];
  __shared__ float Wl[576];
  {
    const float4* Mg = (const float4*)(M + (size_t)b * EDIM);
    float4* Ms = (float4*)Ml;
    for (int i = t; i < EDIM / 4; i += 256) Ms[i] = Mg[i];
    if (t < 72)  ((float4*)Al)[t] = ((const float4*)(A + (size_t)b * 288))[t];
    if (t < 144) ((float4*)Wl)[t] = ((const float4*)W)[t];
  }
  __syncthreads();
  if (t < 72) {
    const int jj = t / 3, i = t - jj * 3;
    float acc = 0.f;
    #pragma unroll
    for (int j = 0; j < NJ; ++j) {
      const float* Ar = &Al[j * 12 + i * 4];
      const int base = (jj * NJ + j) * 3;
      acc += Ar[0] * Ml[base] + Ar[1] * Ml[base + 1]
           + Ar[2] * Ml[base + 2] + Ar[3] * Wl[jj * NJ + j];
    }
    out[(size_t)b * 72 + t] = acc;
  }
}

// =================== fallback: validated monolithic kernel (R5) ===================
__global__ __launch_bounds__(256) void k_all(
    const float* __restrict__ beta,
    const float* __restrict__ theta,
    const float* __restrict__ vt,
    const float* __restrict__ sd,
    const float* __restrict__ pd,
    const float* __restrict__ Jr,
    const float* __restrict__ wts,
    float* __restrict__ out) {
  const int b = blockIdx.x;
  const int t = threadIdx.x;
  __shared__ float vs[NV * 3];
  __shared__ float bl[10];
  __shared__ float pf[207];
  __shared__ float Am[NJ * 12];
  __shared__ float Jl[NJ * 3];
  __shared__ float jpart[72 * 3];
  __shared__ float jred[72];
  if (t < 10) bl[t] = beta[b * 10 + t];
  if (t < 72) jred[t] = 0.f;
  __syncthreads();
  for (int e = t; e < NV * 3; e += 256) {
    float val = vt[e];
    #pragma unroll
    for (int s = 0; s < 10; ++s) val += bl[s] * sd[s * 20670 + e];
    vs[e] = val;
  }
  __syncthreads();
  if (t < 216) {
    const int o = t % 72, part = t / 72;
    const int j = o / 3, c = o - j * 3;
    float local = 0.f;
    for (int v = part; v < NV; v += 3)
      local += Jr[v * NJ + j] * vs[v * 3 + c];
    jpart[o * 3 + part] = local;
  }
  __syncthreads();
  if (t < 72) Jl[t] = jpart[t * 3] + jpart[t * 3 + 1] + jpart[t * 3 + 2];
  __syncthreads();
  const int par[24] = {-1,0,0,0,1,2,3,4,5,6,7,8,9,9,9,12,13,14,16,17,18,19,20,21};
  const int dep[24] = {0,1,1,1,2,2,2,3,3,3,4,4,4,4,4,5,5,5,6,6,7,7,8,8};
  float R[9];
  float Jv[3];
  if (t < NJ) {
    const int j = t;
    const float th0 = theta[b * 72 + j * 3 + 0];
    const float th1 = theta[b * 72 + j * 3 + 1];
    const float th2 = theta[b * 72 + j * 3 + 2];
    const float a0 = th0 + 1e-8f, a1 = th1 + 1e-8f, a2 = th2 + 1e-8f;
    const float angle = sqrtf(a0 * a0 + a1 * a1 + a2 * a2);
    const float inv = 1.0f / angle;
    const float half = 0.5f * angle;
    const float cw = cosf(half), sv = sinf(half);
    float qw = cw, qx = sv * th0 * inv, qy = sv * th1 * inv, qz = sv * th2 * inv;
    const float qn = 1.0f / sqrtf(qw * qw + qx * qx + qy * qy + qz * qz);
    qw *= qn; qx *= qn; qy *= qn; qz *= qn;
    const float w2 = qw * qw, x2 = qx * qx, y2 = qy * qy, z2 = qz * qz;
    const float wx = qw * qx, wy = qw * qy, wz = qw * qz;
    const float xy = qx * qy, xz = qx * qz, yz = qy * qz;
    R[0] = w2 + x2 - y2 - z2; R[1] = 2.f * (xy - wz);   R[2] = 2.f * (xz + wy);
    R[3] = 2.f * (xy + wz);   R[4] = w2 - x2 + y2 - z2; R[5] = 2.f * (yz - wx);
    R[6] = 2.f * (xz - wy);   R[7] = 2.f * (yz + wx);   R[8] = w2 - x2 - y2 + z2;
    #pragma unroll
    for (int c = 0; c < 3; ++c) Jv[c] = Jl[j * 3 + c];
    if (j >= 1) {
      #pragma unroll
      for (int k = 0; k < 9; ++k)
        pf[(j - 1) * 9 + k] = R[k] - ((k == 0 || k == 4 || k == 8) ? 1.f : 0.f);
    }
  }
  __syncthreads();
  for (int lvl = 0; lvl < 9; ++lvl) {
    if (t < NJ && dep[t] == lvl) {
      if (t == 0) {
        #pragma unroll
        for (int i = 0; i < 3; ++i) {
          Am[i * 4 + 0] = R[i * 3 + 0]; Am[i * 4 + 1] = R[i * 3 + 1];
          Am[i * 4 + 2] = R[i * 3 + 2]; Am[i * 4 + 3] = Jv[i];
        }
      } else {
        const int p = par[t];
        const float tr0 = Jv[0] - Jl[p * 3 + 0];
        const float tr1 = Jv[1] - Jl[p * 3 + 1];
        const float tr2 = Jv[2] - Jl[p * 3 + 2];
        float Pr[12];
        #pragma unroll
        for (int k = 0; k < 12; ++k) Pr[k] = Am[p * 12 + k];
        #pragma unroll
        for (int i = 0; i < 3; ++i) {
          const float r0 = Pr[i*4+0], r1 = Pr[i*4+1], r2 = Pr[i*4+2], r3 = Pr[i*4+3];
          Am[t * 12 + i * 4 + 0] = r0 * R[0] + r1 * R[3] + r2 * R[6];
          Am[t * 12 + i * 4 + 1] = r0 * R[1] + r1 * R[4] + r2 * R[7];
          Am[t * 12 + i * 4 + 2] = r0 * R[2] + r1 * R[5] + r2 * R[8];
          Am[t * 12 + i * 4 + 3] = r0 * tr0 + r1 * tr1 + r2 * tr2 + r3;
        }
      }
    }
    __syncthreads();
  }
  if (t < NJ) {
    float res[12];
    #pragma unroll
    for (int k = 0; k < 12; ++k) res[k] = Am[t * 12 + k];
    #pragma unroll
    for (int i = 0; i < 3; ++i) {
      const float r0 = res[i * 4 + 0], r1 = res[i * 4 + 1], r2 = res[i * 4 + 2];
      Am[t * 12 + i * 4 + 3] = res[i * 4 + 3] - (r0 * Jv[0] + r1 * Jv[1] + r2 * Jv[2]);
    }
  }
  __syncthreads();
  for (int r = 0; r < 207; ++r) {
    const float f = pf[r];
    const float* __restrict__ pr = pd + (size_t)r * 20670;
    for (int e = t; e < NV * 3; e += 256) vs[e] += f * pr[e];
  }
  __syncthreads();
  float jacc[72];
  #pragma unroll
  for (int k = 0; k < 72; ++k) jacc[k] = 0.f;
  for (int v = t; v < NV; v += 256) {
    const float vp0 = vs[3 * v + 0];
    const float vp1 = vs[3 * v + 1];
    const float vp2 = vs[3 * v + 2];
    float tA[12];
    #pragma unroll
    for (int k = 0; k < 12; ++k) tA[k] = 0.f;
    const float* __restrict__ wp = wts + (size_t)v * NJ;
    #pragma unroll
    for (int j = 0; j < NJ; ++j) {
      const float wj = wp[j];
      #pragma unroll
      for (int k = 0; k < 12; ++k) tA[k] += wj * Am[j * 12 + k];
    }
    const float vx = tA[0] * vp0 + tA[1] * vp1 + tA[2]  * vp2 + tA[3];
    const float vy = tA[4] * vp0 + tA[5] * vp1 + tA[6]  * vp2 + tA[7];
    const float vz = tA[8] * vp0 + tA[9] * vp1 + tA[10] * vp2 + tA[11];
    const float* __restrict__ jp = Jr + (size_t)v * NJ;
    #pragma unroll
    for (int jj = 0; jj < NJ; ++jj) {
      const float g = jp[jj];
      jacc[jj * 3 + 0] += g * vx;
      jacc[jj * 3 + 1] += g * vy;
      jacc[jj * 3 + 2] += g * vz;
    }
  }
  #pragma unroll
  for (int k = 0; k < 72; ++k) atomicAdd(&jred[k], jacc[k]);
  __syncthreads();
  if (t < 72) out[(size_t)b * 72 + t] = jred[t];
}

extern "C" void kernel_launch(void* const* d_in, const int* in_sizes, int n_in,
                              void* d_out, int out_size, void* d_ws, size_t ws_size,
                              hipStream_t stream) {
  const float* beta  = (const float*)d_in[0];
  const float* theta = (const float*)d_in[1];
  const float* vt    = (const float*)d_in[2];
  const float* sd    = (const float*)d_in[3];
  const float* pd    = (const float*)d_in[4];
  const float* Jr    = (const float*)d_in[5];
  const float* wts   = (const float*)d_in[6];
  float* out = (float*)d_out;
  (void)in_sizes; (void)n_in; (void)out_size;

  if (ws_size >= TOTAL_WS) {
    char* ws = (char*)d_ws;
    float* P  = (float*)(ws + OFF_P);
    float* D  = (float*)(ws + OFF_D);
    float* KQ = (float*)(ws + OFF_KQ);
    float* W  = (float*)(ws + OFF_W);
    float* JQ = (float*)(ws + OFF_JQ);
    float* qT = (float*)(ws + OFF_Q);
    float* A  = (float*)(ws + OFF_A);
    float* M  = (float*)(ws + OFF_M);   // aliases P (P dead after k_reduce)

    k_dfill<<<(NV * DPAD / 4 + 255) / 256, 256, 0, stream>>>(vt, sd, pd, D);
    k_gemm1<<<dim3(11, 5, 8), 256, 0, stream>>>(Jr, wts, D, P);
    k_reduce<<<MM, 256, 0, stream>>>(P, KQ, W, JQ);
    k_chain<<<NB, 64, 0, stream>>>(beta, theta, JQ, qT, A);
    k_mgemm<<<dim3(27, 16), 256, 0, stream>>>(qT, KQ, M);
    k_joints<<<NB, 256, 0, stream>>>(M, A, W, out);
  } else {
    k_all<<<NB, 256, 0, stream>>>(beta, theta, vt, sd, pd, Jr, wts, out);
  }
}

// Round 12
// 240.576 us; speedup vs baseline: 1.2486x; 1.2486x over previous
//
#include <hip/hip_runtime.h>

#define NJ 24
#define NV 6890
#define NB 1024
#define NRQ 218       // 1 + 10 betas + 207 pose
#define QPAD 224
#define MM 600        // 576 (jj,j) pairs + 24 plain-Jr rows
#define NCOLR 654     // real data columns (218*3)
#define NCOL 655      // + ones column at 654
#define DPAD 704      // D row stride (covers 11 x 64 n-tiles)
#define EDIM 1728     // 576*3
#define KCH 862       // vertices per split-K chunk (8 x 862 = 6896 >= 6890)
#define MROWS 640     // P m-rows (10 x 64 tiles)
#define PSLAB (MROWS * DPAD)   // 450,560 floats per z-slab

// ---- workspace layout (bytes), total 40,650,112 (validated guard) ----
constexpr size_t OFF_P  = 0;                       // P  f32 [8][640][704] 14,417,920
constexpr size_t OFF_M  = 0;                       // M  f32 [NB][EDIM]     7,077,888 (aliases P; P dead by then)
constexpr size_t OFF_D  = 17638400;                // D  f32 [NV][DPAD]    19,402,240
constexpr size_t OFF_KQ = 37040640;                // KQ f32 [NRQ][EDIM]    1,506,816
constexpr size_t OFF_W  = 38547456;                // W  f32 [576]              2,304
constexpr size_t OFF_JQ = 38549760;                // JQ f32 [11][72]           3,200
constexpr size_t OFF_Q  = 38552960;                // qT f32 [QPAD][NB]       917,504
constexpr size_t OFF_A  = 39470464;                // A  f32 [NB][288]      1,179,648
constexpr size_t TOTAL_WS = 40650112;

// =================== fast path kernels ===================

// D[v][n] = src_r[v*3+c] (n=r*3+c<654), 1.0 (n==654), 0 pad
__global__ __launch_bounds__(256) void k_dfill(const float* __restrict__ vt,
                                               const float* __restrict__ sd,
                                               const float* __restrict__ pd,
                                               float* __restrict__ D) {
  const int idx = blockIdx.x * 256 + threadIdx.x;
  const int e0 = idx * 4;
  if (e0 >= NV * DPAD) return;
  const int v = e0 / DPAD;
  const int n0 = e0 - v * DPAD;
  float4 r;
  float* pr = (float*)&r;
  #pragma unroll
  for (int u = 0; u < 4; ++u) {
    const int n = n0 + u;
    float val = 0.f;
    if (n < NCOLR) {
      const int rr = n / 3, c = n - 3 * rr;
      const float* src = (rr == 0) ? vt
                       : (rr <= 10) ? (sd + (size_t)(rr - 1) * (NV * 3))
                                    : (pd + (size_t)(rr - 11) * (NV * 3));
      val = src[v * 3 + c];
    } else if (n == NCOLR) {
      val = 1.0f;
    }
    pr[u] = val;
  }
  *(float4*)&D[(size_t)v * DPAD + n0] = r;
}

// P[z][m][n] = sum_{v in chunk z} G[v][m]*D[v][n], G on the fly (vectorized),
// 64x64 tile, 4x4 acc, split-K=8, single-buffered LDS (R10-validated schedule),
// plain float4 stores. Grid (11 n, 10 m, 8 z) = 880 blocks for occupancy.
__global__ __launch_bounds__(256) void k_gemm1(const float* __restrict__ Jr,
                                               const float* __restrict__ wts,
                                               const float* __restrict__ D,
                                               float* __restrict__ P) {
  __shared__ float As[16][64];
  __shared__ float Bs[16][64];
  const int t = threadIdx.x;
  const int n0 = blockIdx.x * 64;
  const int m0 = blockIdx.y * 64;
  const int z  = blockIdx.z;
  const int kbeg = z * KCH;
  const int kend = min(NV, kbeg + KCH);
  const int tm = (t & 15) * 4;        // compute: m offset
  const int tn = (t >> 4) * 4;        // compute: n offset
  const int skk = t >> 4;             // staging: k row (vertex offset)
  const int sc  = (t & 15) * 4;       // staging: 4 columns owned (4-aligned)

  // 4-aligned m-group always lies within one jj-block (jj=m/24, j0=m%24)
  const int mg = m0 + sc;
  int mcase, jjj, j0;
  if (mg < 576)     { mcase = 0; jjj = mg / 24; j0 = mg - 24 * jjj; }
  else if (mg < MM) { mcase = 1; jjj = 0; j0 = mg - 576; }
  else              { mcase = 2; jjj = 0; j0 = 0; }

  float acc[4][4] = {};
  for (int k0 = kbeg; k0 < kend; k0 += 16) {
    const int v = k0 + skk;
    float4 x0 = make_float4(0.f, 0.f, 0.f, 0.f);
    float4 bv4 = x0;
    if (v < kend) {
      const float* __restrict__ jrow = Jr + (size_t)v * NJ;
      if (mcase == 0) {
        const float jv = jrow[jjj];
        const float4 w0 = *(const float4*)(wts + (size_t)v * NJ + j0);
        x0 = make_float4(jv * w0.x, jv * w0.y, jv * w0.z, jv * w0.w);
      } else if (mcase == 1) {
        x0 = *(const float4*)(jrow + j0);
      }
      bv4 = *(const float4*)(D + (size_t)v * DPAD + n0 + sc);
    }
    *(float4*)&As[skk][sc] = x0;
    *(float4*)&Bs[skk][sc] = bv4;
    __syncthreads();
    #pragma unroll
    for (int kk = 0; kk < 16; ++kk) {
      float4 av = *(const float4*)&As[kk][tm];
      float4 bv = *(const float4*)&Bs[kk][tn];
      const float aa[4] = {av.x, av.y, av.z, av.w};
      const float bb[4] = {bv.x, bv.y, bv.z, bv.w};
      #pragma unroll
      for (int i = 0; i < 4; ++i)
        #pragma unroll
        for (int j = 0; j < 4; ++j)
          acc[i][j] += aa[i] * bb[j];
    }
    __syncthreads();
  }
  float* __restrict__ Pz = P + (size_t)z * PSLAB;
  #pragma unroll
  for (int i = 0; i < 4; ++i) {
    const float4 st = make_float4(acc[i][0], acc[i][1], acc[i][2], acc[i][3]);
    *(float4*)&Pz[(size_t)(m0 + tm + i) * DPAD + n0 + tn] = st;
  }
}

// sum the 8 split-K partials and scatter into KQ / W / JQ
__global__ __launch_bounds__(256) void k_reduce(const float* __restrict__ P,
                                                float* __restrict__ KQ,
                                                float* __restrict__ W,
                                                float* __restrict__ JQ) {
  const int m = blockIdx.x;           // 0..599
  for (int n = threadIdx.x; n < NCOL; n += 256) {
    float s = 0.f;
    #pragma unroll
    for (int zz = 0; zz < 8; ++zz)
      s += P[(size_t)zz * PSLAB + (size_t)m * DPAD + n];
    if (m < 576) {
      if (n == NCOLR) W[m] = s;
      else { const int rr = n / 3, c = n - 3 * rr; KQ[(size_t)rr * EDIM + m * 3 + c] = s; }
    } else if (n < 33) {
      const int rr = n / 3, c = n - 3 * rr;
      JQ[rr * 72 + (m - 576) * 3 + c] = s;
    }
  }
}

// per-batch Rodrigues + chain -> A[b][288], qT[r][b] (transposed for k_mgemm)
__global__ __launch_bounds__(64) void k_chain(const float* __restrict__ beta,
                                              const float* __restrict__ theta,
                                              const float* __restrict__ JQ,
                                              float* __restrict__ qT,
                                              float* __restrict__ A) {
  const int b = blockIdx.x;
  const int t = threadIdx.x;
  __shared__ float RES[24][12];
  __shared__ float Jl[24][3];
  const int par[24] = {-1,0,0,0,1,2,3,4,5,6,7,8,9,9,9,12,13,14,16,17,18,19,20,21};
  const int dep[24] = {0,1,1,1,2,2,2,3,3,3,4,4,4,4,4,5,5,5,6,6,7,7,8,8};
  float R[9];
  float Jv[3];
  if (t < 6) qT[(size_t)(NRQ + t) * NB + b] = 0.f;   // zero pad rows 218..223
  if (t < NJ) {
    const int j = t;
    const float th0 = theta[b * 72 + j * 3 + 0];
    const float th1 = theta[b * 72 + j * 3 + 1];
    const float th2 = theta[b * 72 + j * 3 + 2];
    const float a0 = th0 + 1e-8f, a1 = th1 + 1e-8f, a2 = th2 + 1e-8f;
    const float angle = sqrtf(a0 * a0 + a1 * a1 + a2 * a2);
    const float inv = 1.0f / angle;
    const float half = 0.5f * angle;
    const float cw = cosf(half), sv = sinf(half);
    float qw = cw, qx = sv * th0 * inv, qy = sv * th1 * inv, qz = sv * th2 * inv;
    const float qn = 1.0f / sqrtf(qw * qw + qx * qx + qy * qy + qz * qz);
    qw *= qn; qx *= qn; qy *= qn; qz *= qn;
    const float w2 = qw * qw, x2 = qx * qx, y2 = qy * qy, z2 = qz * qz;
    const float wx = qw * qx, wy = qw * qy, wz = qw * qz;
    const float xy = qx * qy, xz = qx * qz, yz = qy * qz;
    R[0] = w2 + x2 - y2 - z2; R[1] = 2.f * (xy - wz);   R[2] = 2.f * (xz + wy);
    R[3] = 2.f * (xy + wz);   R[4] = w2 - x2 + y2 - z2; R[5] = 2.f * (yz - wx);
    R[6] = 2.f * (xz - wy);   R[7] = 2.f * (yz + wx);   R[8] = w2 - x2 - y2 + z2;
    float betaf[10];
    #pragma unroll
    for (int s = 0; s < 10; ++s) betaf[s] = beta[b * 10 + s];
    #pragma unroll
    for (int c = 0; c < 3; ++c) {
      float jv = JQ[j * 3 + c];
      #pragma unroll
      for (int s = 0; s < 10; ++s) jv += betaf[s] * JQ[(1 + s) * 72 + j * 3 + c];
      Jv[c] = jv; Jl[j][c] = jv;
    }
    if (j >= 1) {
      #pragma unroll
      for (int k = 0; k < 9; ++k)
        qT[(size_t)(11 + (j - 1) * 9 + k) * NB + b] = R[k] - ((k == 0 || k == 4 || k == 8) ? 1.f : 0.f);
    }
    if (j == 0) qT[b] = 1.f;
    if (j < 10) qT[(size_t)(1 + j) * NB + b] = betaf[j];
  }
  __syncthreads();
  for (int lvl = 0; lvl < 9; ++lvl) {
    if (t < NJ && dep[t] == lvl) {
      if (t == 0) {
        #pragma unroll
        for (int i = 0; i < 3; ++i) {
          RES[0][i * 4 + 0] = R[i * 3 + 0]; RES[0][i * 4 + 1] = R[i * 3 + 1];
          RES[0][i * 4 + 2] = R[i * 3 + 2]; RES[0][i * 4 + 3] = Jv[i];
        }
      } else {
        const int p = par[t];
        const float tr0 = Jv[0] - Jl[p][0];
        const float tr1 = Jv[1] - Jl[p][1];
        const float tr2 = Jv[2] - Jl[p][2];
        float Pr[12];
        #pragma unroll
        for (int k = 0; k < 12; ++k) Pr[k] = RES[p][k];
        #pragma unroll
        for (int i = 0; i < 3; ++i) {
          const float r0 = Pr[i*4+0], r1 = Pr[i*4+1], r2 = Pr[i*4+2], r3 = Pr[i*4+3];
          RES[t][i * 4 + 0] = r0 * R[0] + r1 * R[3] + r2 * R[6];
          RES[t][i * 4 + 1] = r0 * R[1] + r1 * R[4] + r2 * R[7];
          RES[t][i * 4 + 2] = r0 * R[2] + r1 * R[5] + r2 * R[8];
          RES[t][i * 4 + 3] = r0 * tr0 + r1 * tr1 + r2 * tr2 + r3;
        }
      }
    }
    __syncthreads();
  }
  if (t < NJ) {
    float* Ab = A + (size_t)b * 288 + t * 12;
    #pragma unroll
    for (int i = 0; i < 3; ++i) {
      const float r0 = RES[t][i*4+0], r1 = RES[t][i*4+1], r2 = RES[t][i*4+2];
      const float ti = RES[t][i*4+3] - (r0 * Jv[0] + r1 * Jv[1] + r2 * Jv[2]);
      Ab[i*4+0] = r0; Ab[i*4+1] = r1; Ab[i*4+2] = r2; Ab[i*4+3] = ti;
    }
  }
}

// M[b][e] = sum_r qT[r][b] * KQ[r][e]; 64(b) x 64(e) tile, 4x4 acc, K=224
__global__ __launch_bounds__(256) void k_mgemm(const float* __restrict__ qT,
                                               const float* __restrict__ KQ,
                                               float* __restrict__ M) {
  __shared__ float Qs[16][64];
  __shared__ float Ks[16][64];
  const int t = threadIdx.x;
  const int e0 = blockIdx.x * 64;
  const int b0 = blockIdx.y * 64;
  const int tb = (t & 15) * 4;
  const int te = (t >> 4) * 4;
  const int skk = t >> 4;
  const int sc  = (t & 15) * 4;
  float acc[4][4] = {};
  for (int k0 = 0; k0 < QPAD; k0 += 16) {
    const int k = k0 + skk;
    *(float4*)&Qs[skk][sc] = *(const float4*)&qT[(size_t)k * NB + b0 + sc];
    if (k < NRQ) *(float4*)&Ks[skk][sc] = *(const float4*)&KQ[(size_t)k * EDIM + e0 + sc];
    else         *(float4*)&Ks[skk][sc] = make_float4(0.f, 0.f, 0.f, 0.f);
    __syncthreads();
    #pragma unroll
    for (int kk = 0; kk < 16; ++kk) {
      float4 qv = *(const float4*)&Qs[kk][tb];
      float4 kv = *(const float4*)&Ks[kk][te];
      const float qa[4] = {qv.x, qv.y, qv.z, qv.w};
      const float ka[4] = {kv.x, kv.y, kv.z, kv.w};
      #pragma unroll
      for (int i = 0; i < 4; ++i)
        #pragma unroll
        for (int j = 0; j < 4; ++j)
          acc[i][j] += qa[i] * ka[j];
    }
    __syncthreads();
  }
  #pragma unroll
  for (int i = 0; i < 4; ++i) {
    float4 st = make_float4(acc[i][0], acc[i][1], acc[i][2], acc[i][3]);
    *(float4*)&M[(size_t)(b0 + tb + i) * EDIM + e0 + te] = st;
  }
}

// joints[b,jj,i] = sum_j( A[b,j,i,:3] . M[b,(jj,j)*3..] + A[b,j,i,3]*W[jj,j] )
// one batch per block: 10.4 KB LDS, 1024 blocks
__global__ __launch_bounds__(256) void k_joints(const float* __restrict__ M,
                                                const float* __restrict__ A,
                                                const float* __restrict__ W,
                                                float* __restrict__ out) {
  const int b = blockIdx.x;
  const int t = threadIdx.x;
  __shared__ float Ml[EDIM];
  __shared__ float Al[288];
  __shared__ float Wl[576];
  {
    const float4* Mg = (const float4*)(M + (size_t)b * EDIM);
    float4* Ms = (float4*)Ml;
    for (int i = t; i < EDIM / 4; i += 256) Ms[i] = Mg[i];
    if (t < 72)  ((float4*)Al)[t] = ((const float4*)(A + (size_t)b * 288))[t];
    if (t < 144) ((float4*)Wl)[t] = ((const float4*)W)[t];
  }
  __syncthreads();
  if (t < 72) {
    const int jj = t / 3, i = t - jj * 3;
    float acc = 0.f;
    #pragma unroll
    for (int j = 0; j < NJ; ++j) {
      const float* Ar = &Al[j * 12 + i * 4];
      const int base = (jj * NJ + j) * 3;
      acc += Ar[0] * Ml[base] + Ar[1] * Ml[base + 1]
           + Ar[2] * Ml[base + 2] + Ar[3] * Wl[jj * NJ + j];
    }
    out[(size_t)b * 72 + t] = acc;
  }
}

// =================== fallback: validated monolithic kernel (R5) ===================
__global__ __launch_bounds__(256) void k_all(
    const float* __restrict__ beta,
    const float* __restrict__ theta,
    const float* __restrict__ vt,
    const float* __restrict__ sd,
    const float* __restrict__ pd,
    const float* __restrict__ Jr,
    const float* __restrict__ wts,
    float* __restrict__ out) {
  const int b = blockIdx.x;
  const int t = threadIdx.x;
  __shared__ float vs[NV * 3];
  __shared__ float bl[10];
  __shared__ float pf[207];
  __shared__ float Am[NJ * 12];
  __shared__ float Jl[NJ * 3];
  __shared__ float jpart[72 * 3];
  __shared__ float jred[72];
  if (t < 10) bl[t] = beta[b * 10 + t];
  if (t < 72) jred[t] = 0.f;
  __syncthreads();
  for (int e = t; e < NV * 3; e += 256) {
    float val = vt[e];
    #pragma unroll
    for (int s = 0; s < 10; ++s) val += bl[s] * sd[s * 20670 + e];
    vs[e] = val;
  }
  __syncthreads();
  if (t < 216) {
    const int o = t % 72, part = t / 72;
    const int j = o / 3, c = o - j * 3;
    float local = 0.f;
    for (int v = part; v < NV; v += 3)
      local += Jr[v * NJ + j] * vs[v * 3 + c];
    jpart[o * 3 + part] = local;
  }
  __syncthreads();
  if (t < 72) Jl[t] = jpart[t * 3] + jpart[t * 3 + 1] + jpart[t * 3 + 2];
  __syncthreads();
  const int par[24] = {-1,0,0,0,1,2,3,4,5,6,7,8,9,9,9,12,13,14,16,17,18,19,20,21};
  const int dep[24] = {0,1,1,1,2,2,2,3,3,3,4,4,4,4,4,5,5,5,6,6,7,7,8,8};
  float R[9];
  float Jv[3];
  if (t < NJ) {
    const int j = t;
    const float th0 = theta[b * 72 + j * 3 + 0];
    const float th1 = theta[b * 72 + j * 3 + 1];
    const float th2 = theta[b * 72 + j * 3 + 2];
    const float a0 = th0 + 1e-8f, a1 = th1 + 1e-8f, a2 = th2 + 1e-8f;
    const float angle = sqrtf(a0 * a0 + a1 * a1 + a2 * a2);
    const float inv = 1.0f / angle;
    const float half = 0.5f * angle;
    const float cw = cosf(half), sv = sinf(half);
    float qw = cw, qx = sv * th0 * inv, qy = sv * th1 * inv, qz = sv * th2 * inv;
    const float qn = 1.0f / sqrtf(qw * qw + qx * qx + qy * qy + qz * qz);
    qw *= qn; qx *= qn; qy *= qn; qz *= qn;
    const float w2 = qw * qw, x2 = qx * qx, y2 = qy * qy, z2 = qz * qz;
    const float wx = qw * qx, wy = qw * qy, wz = qw * qz;
    const float xy = qx * qy, xz = qx * qz, yz = qy * qz;
    R[0] = w2 + x2 - y2 - z2; R[1] = 2.f * (xy - wz);   R[2] = 2.f * (xz + wy);
    R[3] = 2.f * (xy + wz);   R[4] = w2 - x2 + y2 - z2; R[5] = 2.f * (yz - wx);
    R[6] = 2.f * (xz - wy);   R[7] = 2.f * (yz + wx);   R[8] = w2 - x2 - y2 + z2;
    #pragma unroll
    for (int c = 0; c < 3; ++c) Jv[c] = Jl[j * 3 + c];
    if (j >= 1) {
      #pragma unroll
      for (int k = 0; k < 9; ++k)
        pf[(j - 1) * 9 + k] = R[k] - ((k == 0 || k == 4 || k == 8) ? 1.f : 0.f);
    }
  }
  __syncthreads();
  for (int lvl = 0; lvl < 9; ++lvl) {
    if (t < NJ && dep[t] == lvl) {
      if (t == 0) {
        #pragma unroll
        for (int i = 0; i < 3; ++i) {
          Am[i * 4 + 0] = R[i * 3 + 0]; Am[i * 4 + 1] = R[i * 3 + 1];
          Am[i * 4 + 2] = R[i * 3 + 2]; Am[i * 4 + 3] = Jv[i];
        }
      } else {
        const int p = par[t];
        const float tr0 = Jv[0] - Jl[p * 3 + 0];
        const float tr1 = Jv[1] - Jl[p * 3 + 1];
        const float tr2 = Jv[2] - Jl[p * 3 + 2];
        float Pr[12];
        #pragma unroll
        for (int k = 0; k < 12; ++k) Pr[k] = Am[p * 12 + k];
        #pragma unroll
        for (int i = 0; i < 3; ++i) {
          const float r0 = Pr[i*4+0], r1 = Pr[i*4+1], r2 = Pr[i*4+2], r3 = Pr[i*4+3];
          Am[t * 12 + i * 4 + 0] = r0 * R[0] + r1 * R[3] + r2 * R[6];
          Am[t * 12 + i * 4 + 1] = r0 * R[1] + r1 * R[4] + r2 * R[7];
          Am[t * 12 + i * 4 + 2] = r0 * R[2] + r1 * R[5] + r2 * R[8];
          Am[t * 12 + i * 4 + 3] = r0 * tr0 + r1 * tr1 + r2 * tr2 + r3;
        }
      }
    }
    __syncthreads();
  }
  if (t < NJ) {
    float res[12];
    #pragma unroll
    for (int k = 0; k < 12; ++k) res[k] = Am[t * 12 + k];
    #pragma unroll
    for (int i = 0; i < 3; ++i) {
      const float r0 = res[i * 4 + 0], r1 = res[i * 4 + 1], r2 = res[i * 4 + 2];
      Am[t * 12 + i * 4 + 3] = res[i * 4 + 3] - (r0 * Jv[0] + r1 * Jv[1] + r2 * Jv[2]);
    }
  }
  __syncthreads();
  for (int r = 0; r < 207; ++r) {
    const float f = pf[r];
    const float* __restrict__ pr = pd + (size_t)r * 20670;
    for (int e = t; e < NV * 3; e += 256) vs[e] += f * pr[e];
  }
  __syncthreads();
  float jacc[72];
  #pragma unroll
  for (int k = 0; k < 72; ++k) jacc[k] = 0.f;
  for (int v = t; v < NV; v += 256) {
    const float vp0 = vs[3 * v + 0];
    const float vp1 = vs[3 * v + 1];
    const float vp2 = vs[3 * v + 2];
    float tA[12];
    #pragma unroll
    for (int k = 0; k < 12; ++k) tA[k] = 0.f;
    const float* __restrict__ wp = wts + (size_t)v * NJ;
    #pragma unroll
    for (int j = 0; j < NJ; ++j) {
      const float wj = wp[j];
      #pragma unroll
      for (int k = 0; k < 12; ++k) tA[k] += wj * Am[j * 12 + k];
    }
    const float vx = tA[0] * vp0 + tA[1] * vp1 + tA[2]  * vp2 + tA[3];
    const float vy = tA[4] * vp0 + tA[5] * vp1 + tA[6]  * vp2 + tA[7];
    const float vz = tA[8] * vp0 + tA[9] * vp1 + tA[10] * vp2 + tA[11];
    const float* __restrict__ jp = Jr + (size_t)v * NJ;
    #pragma unroll
    for (int jj = 0; jj < NJ; ++jj) {
      const float g = jp[jj];
      jacc[jj * 3 + 0] += g * vx;
      jacc[jj * 3 + 1] += g * vy;
      jacc[jj * 3 + 2] += g * vz;
    }
  }
  #pragma unroll
  for (int k = 0; k < 72; ++k) atomicAdd(&jred[k], jacc[k]);
  __syncthreads();
  if (t < 72) out[(size_t)b * 72 + t] = jred[t];
}

extern "C" void kernel_launch(void* const* d_in, const int* in_sizes, int n_in,
                              void* d_out, int out_size, void* d_ws, size_t ws_size,
                              hipStream_t stream) {
  const float* beta  = (const float*)d_in[0];
  const float* theta = (const float*)d_in[1];
  const float* vt    = (const float*)d_in[2];
  const float* sd    = (const float*)d_in[3];
  const float* pd    = (const float*)d_in[4];
  const float* Jr    = (const float*)d_in[5];
  const float* wts   = (const float*)d_in[6];
  float* out = (float*)d_out;
  (void)in_sizes; (void)n_in; (void)out_size;

  if (ws_size >= TOTAL_WS) {
    char* ws = (char*)d_ws;
    float* P  = (float*)(ws + OFF_P);
    float* D  = (float*)(ws + OFF_D);
    float* KQ = (float*)(ws + OFF_KQ);
    float* W  = (float*)(ws + OFF_W);
    float* JQ = (float*)(ws + OFF_JQ);
    float* qT = (float*)(ws + OFF_Q);
    float* A  = (float*)(ws + OFF_A);
    float* M  = (float*)(ws + OFF_M);   // aliases P (P dead after k_reduce)

    k_dfill<<<(NV * DPAD / 4 + 255) / 256, 256, 0, stream>>>(vt, sd, pd, D);
    k_gemm1<<<dim3(11, 10, 8), 256, 0, stream>>>(Jr, wts, D, P);
    k_reduce<<<MM, 256, 0, stream>>>(P, KQ, W, JQ);
    k_chain<<<NB, 64, 0, stream>>>(beta, theta, JQ, qT, A);
    k_mgemm<<<dim3(27, 16), 256, 0, stream>>>(qT, KQ, M);
    k_joints<<<NB, 256, 0, stream>>>(M, A, W, out);
  } else {
    k_all<<<NB, 256, 0, stream>>>(beta, theta, vt, sd, pd, Jr, wts, out);
  }
}

// Round 14
// 217.153 us; speedup vs baseline: 1.3833x; 1.1079x over previous
//
#include <hip/hip_runtime.h>

#define NJ 24
#define NV 6890
#define NB 1024
#define NRQ 218       // 1 + 10 betas + 207 pose
#define QPAD 224
#define MM 600        // 576 (jj,j) pairs + 24 plain-Jr rows
#define NCOLR 654     // real data columns (218*3)
#define NCOL 655      // + ones column at 654
#define DPAD 704      // D row stride (covers 11 x 64 n-tiles)
#define EDIM 1728     // 576*3
#define NZ 10         // split-K chunks
#define KCH 689       // vertices per chunk (10 x 689 = 6890)
#define MROWS 640     // P m-rows (10 x 64 tiles)
#define PPAD 656      // P row stride (n-tile 640 stores ONLY cols < 656 — see guard)
#define PSLAB (MROWS * PPAD)   // 419,840 floats per z-slab

// ---- workspace layout (bytes), total 40,650,112 (validated guard) ----
constexpr size_t OFF_P  = 0;                       // P  f32 [10][640][656] 16,793,600
constexpr size_t OFF_M  = 0;                       // M  f32 [NB][EDIM]      7,077,888 (aliases P)
constexpr size_t OFF_D  = 17638400;                // D  f32 [NV][DPAD]     19,402,240
constexpr size_t OFF_KQ = 37040640;                // KQ f32 [NRQ][EDIM]     1,506,816
constexpr size_t OFF_W  = 38547456;                // W  f32 [576]               2,304
constexpr size_t OFF_JQ = 38549760;                // JQ f32 [11][72]            3,200
constexpr size_t OFF_Q  = 38552960;                // qT f32 [QPAD][NB]        917,504
constexpr size_t OFF_A  = 39470464;                // A  f32 [NB][288]       1,179,648
constexpr size_t TOTAL_WS = 40650112;

// =================== fast path kernels ===================

// D[v][n] = src_r[3v+c] (n=3r+c<654), 1.0 (n==654), 0 pad — LDS-tiled transpose,
// coalesced reads AND writes. Grid: (108 v-tiles, 10 r-tiles of 24).
__global__ __launch_bounds__(256) void k_dfill(const float* __restrict__ vt,
                                               const float* __restrict__ sd,
                                               const float* __restrict__ pd,
                                               float* __restrict__ D) {
  __shared__ float Dt[64][76];   // 76-pad breaks LDS bank patterns
  const int t  = threadIdx.x;
  const int v0 = blockIdx.x * 64;
  const int rt = blockIdx.y;            // 0..9
  const int r0 = rt * 24;
  // read phase: 24 r-rows x 48 float4 (192 floats = 64 v x 3 c), contiguous
  for (int lin = t; lin < 24 * 48; lin += 256) {
    const int r  = lin / 48;
    const int i4 = lin - r * 48;
    const int rr = r0 + r;
    float4 val = make_float4(0.f, 0.f, 0.f, 0.f);
    float* pv = (float*)&val;
    if (rr < 218) {
      const float* __restrict__ S = (rr == 0) ? vt
                                  : (rr <= 10) ? (sd + (size_t)(rr - 1) * 20670)
                                               : (pd + (size_t)(rr - 11) * 20670);
      const int base = 3 * v0 + 4 * i4;
      if (base + 3 < NV * 3) {
        val = *(const float4*)(S + base);
      } else {
        #pragma unroll
        for (int u = 0; u < 4; ++u) if (base + u < NV * 3) pv[u] = S[base + u];
      }
    } else if (rr == 218) {               // ones column (c==0 -> n=654)
      #pragma unroll
      for (int u = 0; u < 4; ++u) pv[u] = (((4 * i4 + u) % 3) == 0) ? 1.0f : 0.f;
    }
    #pragma unroll
    for (int u = 0; u < 4; ++u) {
      const int i = 4 * i4 + u;           // i = 3*vv + c
      Dt[i / 3][3 * r + (i % 3)] = pv[u];
    }
  }
  __syncthreads();
  // write phase: 64 vv x 18 float4 (72 n-cols starting at 72*rt), coalesced
  for (int lin = t; lin < 64 * 18; lin += 256) {
    const int vv = lin / 18;
    const int n4 = lin - vv * 18;
    const int v  = v0 + vv;
    const int n  = 72 * rt + 4 * n4;
    if (v < NV && n < DPAD)
      *(float4*)&D[(size_t)v * DPAD + n] = *(const float4*)&Dt[vv][4 * n4];
  }
}

// P[z][m][n] = sum_{v in chunk z} G[v][m]*D[v][n], G on the fly (vectorized),
// 64x64 tile, 4x4 acc, LDS depth 32 (2 barriers per 32 k), split-K=10,
// plain float4 stores. Grid (11 n, 10 m, 10 z) = 1100 blocks.
// R13 BUG FIX: the n0=640 tile must store only columns < PPAD(656); columns
// >= 656 are provably zero (D zero-pad) and never read by k_reduce (n<=654).
__global__ __launch_bounds__(256) void k_gemm1(const float* __restrict__ Jr,
                                               const float* __restrict__ wts,
                                               const float* __restrict__ D,
                                               float* __restrict__ P) {
  __shared__ float As[32][64];
  __shared__ float Bs[32][64];
  const int t = threadIdx.x;
  const int n0 = blockIdx.x * 64;
  const int m0 = blockIdx.y * 64;
  const int z  = blockIdx.z;
  const int kbeg = z * KCH;
  const int kend = min(NV, kbeg + KCH);
  const int tm = (t & 15) * 4;
  const int tn = (t >> 4) * 4;
  const int skk = t >> 4;             // staging row base (0..15)
  const int sc  = (t & 15) * 4;       // 4 columns owned (4-aligned)

  // 4-aligned m-group lies within one jj-block (jj=m/24, j0=m%24)
  const int mg = m0 + sc;
  int mcase, jjj, j0;
  if (mg < 576)     { mcase = 0; jjj = mg / 24; j0 = mg - 24 * jjj; }
  else if (mg < MM) { mcase = 1; jjj = 0; j0 = mg - 576; }
  else              { mcase = 2; jjj = 0; j0 = 0; }

  float acc[4][4] = {};
  for (int k0 = kbeg; k0 < kend; k0 += 32) {
    #pragma unroll
    for (int h = 0; h < 2; ++h) {
      const int v = k0 + skk + h * 16;
      float4 x0 = make_float4(0.f, 0.f, 0.f, 0.f);
      float4 bv4 = x0;
      if (v < kend) {
        const float* __restrict__ jrow = Jr + (size_t)v * NJ;
        if (mcase == 0) {
          const float jv = jrow[jjj];
          const float4 w0 = *(const float4*)(wts + (size_t)v * NJ + j0);
          x0 = make_float4(jv * w0.x, jv * w0.y, jv * w0.z, jv * w0.w);
        } else if (mcase == 1) {
          x0 = *(const float4*)(jrow + j0);
        }
        bv4 = *(const float4*)(D + (size_t)v * DPAD + n0 + sc);
      }
      *(float4*)&As[skk + h * 16][sc] = x0;
      *(float4*)&Bs[skk + h * 16][sc] = bv4;
    }
    __syncthreads();
    #pragma unroll
    for (int kk = 0; kk < 32; ++kk) {
      float4 av = *(const float4*)&As[kk][tm];
      float4 bv = *(const float4*)&Bs[kk][tn];
      const float aa[4] = {av.x, av.y, av.z, av.w};
      const float bb[4] = {bv.x, bv.y, bv.z, bv.w};
      #pragma unroll
      for (int i = 0; i < 4; ++i)
        #pragma unroll
        for (int j = 0; j < 4; ++j)
          acc[i][j] += aa[i] * bb[j];
    }
    __syncthreads();
  }
  if (n0 + tn + 3 < PPAD) {             // drop cols >= 656 (zero & unused)
    float* __restrict__ Pz = P + (size_t)z * PSLAB;
    #pragma unroll
    for (int i = 0; i < 4; ++i) {
      const float4 st = make_float4(acc[i][0], acc[i][1], acc[i][2], acc[i][3]);
      *(float4*)&Pz[(size_t)(m0 + tm + i) * PPAD + n0 + tn] = st;
    }
  }
}

// sum the split-K partials and scatter into KQ / W / JQ
__global__ __launch_bounds__(256) void k_reduce(const float* __restrict__ P,
                                                float* __restrict__ KQ,
                                                float* __restrict__ W,
                                                float* __restrict__ JQ) {
  const int m = blockIdx.x;           // 0..599
  for (int n = threadIdx.x; n < NCOL; n += 256) {
    float s = 0.f;
    #pragma unroll
    for (int zz = 0; zz < NZ; ++zz)
      s += P[(size_t)zz * PSLAB + (size_t)m * PPAD + n];
    if (m < 576) {
      if (n == NCOLR) W[m] = s;
      else { const int rr = n / 3, c = n - 3 * rr; KQ[(size_t)rr * EDIM + m * 3 + c] = s; }
    } else if (n < 33) {
      const int rr = n / 3, c = n - 3 * rr;
      JQ[rr * 72 + (m - 576) * 3 + c] = s;
    }
  }
}

// per-batch Rodrigues + chain -> A[b][288], qT[r][b] (transposed for k_mgemm)
__global__ __launch_bounds__(64) void k_chain(const float* __restrict__ beta,
                                              const float* __restrict__ theta,
                                              const float* __restrict__ JQ,
                                              float* __restrict__ qT,
                                              float* __restrict__ A) {
  const int b = blockIdx.x;
  const int t = threadIdx.x;
  __shared__ float RES[24][12];
  __shared__ float Jl[24][3];
  const int par[24] = {-1,0,0,0,1,2,3,4,5,6,7,8,9,9,9,12,13,14,16,17,18,19,20,21};
  const int dep[24] = {0,1,1,1,2,2,2,3,3,3,4,4,4,4,4,5,5,5,6,6,7,7,8,8};
  float R[9];
  float Jv[3];
  if (t < 6) qT[(size_t)(NRQ + t) * NB + b] = 0.f;   // zero pad rows 218..223
  if (t < NJ) {
    const int j = t;
    const float th0 = theta[b * 72 + j * 3 + 0];
    const float th1 = theta[b * 72 + j * 3 + 1];
    const float th2 = theta[b * 72 + j * 3 + 2];
    const float a0 = th0 + 1e-8f, a1 = th1 + 1e-8f, a2 = th2 + 1e-8f;
    const float angle = sqrtf(a0 * a0 + a1 * a1 + a2 * a2);
    const float inv = 1.0f / angle;
    const float half = 0.5f * angle;
    const float cw = cosf(half), sv = sinf(half);
    float qw = cw, qx = sv * th0 * inv, qy = sv * th1 * inv, qz = sv * th2 * inv;
    const float qn = 1.0f / sqrtf(qw * qw + qx * qx + qy * qy + qz * qz);
    qw *= qn; qx *= qn; qy *= qn; qz *= qn;
    const float w2 = qw * qw, x2 = qx * qx, y2 = qy * qy, z2 = qz * qz;
    const float wx = qw * qx, wy = qw * qy, wz = qw * qz;
    const float xy = qx * qy, xz = qx * qz, yz = qy * qz;
    R[0] = w2 + x2 - y2 - z2; R[1] = 2.f * (xy - wz);   R[2] = 2.f * (xz + wy);
    R[3] = 2.f * (xy + wz);   R[4] = w2 - x2 + y2 - z2; R[5] = 2.f * (yz - wx);
    R[6] = 2.f * (xz - wy);   R[7] = 2.f * (yz + wx);   R[8] = w2 - x2 - y2 + z2;
    float betaf[10];
    #pragma unroll
    for (int s = 0; s < 10; ++s) betaf[s] = beta[b * 10 + s];
    #pragma unroll
    for (int c = 0; c < 3; ++c) {
      float jv = JQ[j * 3 + c];
      #pragma unroll
      for (int s = 0; s < 10; ++s) jv += betaf[s] * JQ[(1 + s) * 72 + j * 3 + c];
      Jv[c] = jv; Jl[j][c] = jv;
    }
    if (j >= 1) {
      #pragma unroll
      for (int k = 0; k < 9; ++k)
        qT[(size_t)(11 + (j - 1) * 9 + k) * NB + b] = R[k] - ((k == 0 || k == 4 || k == 8) ? 1.f : 0.f);
    }
    if (j == 0) qT[b] = 1.f;
    if (j < 10) qT[(size_t)(1 + j) * NB + b] = betaf[j];
  }
  __syncthreads();
  for (int lvl = 0; lvl < 9; ++lvl) {
    if (t < NJ && dep[t] == lvl) {
      if (t == 0) {
        #pragma unroll
        for (int i = 0; i < 3; ++i) {
          RES[0][i * 4 + 0] = R[i * 3 + 0]; RES[0][i * 4 + 1] = R[i * 3 + 1];
          RES[0][i * 4 + 2] = R[i * 3 + 2]; RES[0][i * 4 + 3] = Jv[i];
        }
      } else {
        const int p = par[t];
        const float tr0 = Jv[0] - Jl[p][0];
        const float tr1 = Jv[1] - Jl[p][1];
        const float tr2 = Jv[2] - Jl[p][2];
        float Pr[12];
        #pragma unroll
        for (int k = 0; k < 12; ++k) Pr[k] = RES[p][k];
        #pragma unroll
        for (int i = 0; i < 3; ++i) {
          const float r0 = Pr[i*4+0], r1 = Pr[i*4+1], r2 = Pr[i*4+2], r3 = Pr[i*4+3];
          RES[t][i * 4 + 0] = r0 * R[0] + r1 * R[3] + r2 * R[6];
          RES[t][i * 4 + 1] = r0 * R[1] + r1 * R[4] + r2 * R[7];
          RES[t][i * 4 + 2] = r0 * R[2] + r1 * R[5] + r2 * R[8];
          RES[t][i * 4 + 3] = r0 * tr0 + r1 * tr1 + r2 * tr2 + r3;
        }
      }
    }
    __syncthreads();
  }
  if (t < NJ) {
    float* Ab = A + (size_t)b * 288 + t * 12;
    #pragma unroll
    for (int i = 0; i < 3; ++i) {
      const float r0 = RES[t][i*4+0], r1 = RES[t][i*4+1], r2 = RES[t][i*4+2];
      const float ti = RES[t][i*4+3] - (r0 * Jv[0] + r1 * Jv[1] + r2 * Jv[2]);
      Ab[i*4+0] = r0; Ab[i*4+1] = r1; Ab[i*4+2] = r2; Ab[i*4+3] = ti;
    }
  }
}

// M[b][e] = sum_r qT[r][b] * KQ[r][e]; 64(b) x 64(e) tile, 4x4 acc, K=224
__global__ __launch_bounds__(256) void k_mgemm(const float* __restrict__ qT,
                                               const float* __restrict__ KQ,
                                               float* __restrict__ M) {
  __shared__ float Qs[16][64];
  __shared__ float Ks[16][64];
  const int t = threadIdx.x;
  const int e0 = blockIdx.x * 64;
  const int b0 = blockIdx.y * 64;
  const int tb = (t & 15) * 4;
  const int te = (t >> 4) * 4;
  const int skk = t >> 4;
  const int sc  = (t & 15) * 4;
  float acc[4][4] = {};
  for (int k0 = 0; k0 < QPAD; k0 += 16) {
    const int k = k0 + skk;
    *(float4*)&Qs[skk][sc] = *(const float4*)&qT[(size_t)k * NB + b0 + sc];
    if (k < NRQ) *(float4*)&Ks[skk][sc] = *(const float4*)&KQ[(size_t)k * EDIM + e0 + sc];
    else         *(float4*)&Ks[skk][sc] = make_float4(0.f, 0.f, 0.f, 0.f);
    __syncthreads();
    #pragma unroll
    for (int kk = 0; kk < 16; ++kk) {
      float4 qv = *(const float4*)&Qs[kk][tb];
      float4 kv = *(const float4*)&Ks[kk][te];
      const float qa[4] = {qv.x, qv.y, qv.z, qv.w};
      const float ka[4] = {kv.x, kv.y, kv.z, kv.w};
      #pragma unroll
      for (int i = 0; i < 4; ++i)
        #pragma unroll
        for (int j = 0; j < 4; ++j)
          acc[i][j] += qa[i] * ka[j];
    }
    __syncthreads();
  }
  #pragma unroll
  for (int i = 0; i < 4; ++i) {
    float4 st = make_float4(acc[i][0], acc[i][1], acc[i][2], acc[i][3]);
    *(float4*)&M[(size_t)(b0 + tb + i) * EDIM + e0 + te] = st;
  }
}

// joints[b,jj,i] = sum_j( A[b,j,i,:3] . M[b,(jj,j)*3..] + A[b,j,i,3]*W[jj,j] )
__global__ __launch_bounds__(256) void k_joints(const float* __restrict__ M,
                                                const float* __restrict__ A,
                                                const float* __restrict__ W,
                                                float* __restrict__ out) {
  const int b = blockIdx.x;
  const int t = threadIdx.x;
  __shared__ float Ml[EDIM];
  __shared__ float Al[288];
  __shared__ float Wl[576];
  {
    const float4* Mg = (const float4*)(M + (size_t)b * EDIM);
    float4* Ms = (float4*)Ml;
    for (int i = t; i < EDIM / 4; i += 256) Ms[i] = Mg[i];
    if (t < 72)  ((float4*)Al)[t] = ((const float4*)(A + (size_t)b * 288))[t];
    if (t < 144) ((float4*)Wl)[t] = ((const float4*)W)[t];
  }
  __syncthreads();
  if (t < 72) {
    const int jj = t / 3, i = t - jj * 3;
    float acc = 0.f;
    #pragma unroll
    for (int j = 0; j < NJ; ++j) {
      const float* Ar = &Al[j * 12 + i * 4];
      const int base = (jj * NJ + j) * 3;
      acc += Ar[0] * Ml[base] + Ar[1] * Ml[base + 1]
           + Ar[2] * Ml[base + 2] + Ar[3] * Wl[jj * NJ + j];
    }
    out[(size_t)b * 72 + t] = acc;
  }
}

// =================== fallback: validated monolithic kernel (R5) ===================
__global__ __launch_bounds__(256) void k_all(
    const float* __restrict__ beta,
    const float* __restrict__ theta,
    const float* __restrict__ vt,
    const float* __restrict__ sd,
    const float* __restrict__ pd,
    const float* __restrict__ Jr,
    const float* __restrict__ wts,
    float* __restrict__ out) {
  const int b = blockIdx.x;
  const int t = threadIdx.x;
  __shared__ float vs[NV * 3];
  __shared__ float bl[10];
  __shared__ float pf[207];
  __shared__ float Am[NJ * 12];
  __shared__ float Jl[NJ * 3];
  __shared__ float jpart[72 * 3];
  __shared__ float jred[72];
  if (t < 10) bl[t] = beta[b * 10 + t];
  if (t < 72) jred[t] = 0.f;
  __syncthreads();
  for (int e = t; e < NV * 3; e += 256) {
    float val = vt[e];
    #pragma unroll
    for (int s = 0; s < 10; ++s) val += bl[s] * sd[s * 20670 + e];
    vs[e] = val;
  }
  __syncthreads();
  if (t < 216) {
    const int o = t % 72, part = t / 72;
    const int j = o / 3, c = o - j * 3;
    float local = 0.f;
    for (int v = part; v < NV; v += 3)
      local += Jr[v * NJ + j] * vs[v * 3 + c];
    jpart[o * 3 + part] = local;
  }
  __syncthreads();
  if (t < 72) Jl[t] = jpart[t * 3] + jpart[t * 3 + 1] + jpart[t * 3 + 2];
  __syncthreads();
  const int par[24] = {-1,0,0,0,1,2,3,4,5,6,7,8,9,9,9,12,13,14,16,17,18,19,20,21};
  const int dep[24] = {0,1,1,1,2,2,2,3,3,3,4,4,4,4,4,5,5,5,6,6,7,7,8,8};
  float R[9];
  float Jv[3];
  if (t < NJ) {
    const int j = t;
    const float th0 = theta[b * 72 + j * 3 + 0];
    const float th1 = theta[b * 72 + j * 3 + 1];
    const float th2 = theta[b * 72 + j * 3 + 2];
    const float a0 = th0 + 1e-8f, a1 = th1 + 1e-8f, a2 = th2 + 1e-8f;
    const float angle = sqrtf(a0 * a0 + a1 * a1 + a2 * a2);
    const float inv = 1.0f / angle;
    const float half = 0.5f * angle;
    const float cw = cosf(half), sv = sinf(half);
    float qw = cw, qx = sv * th0 * inv, qy = sv * th1 * inv, qz = sv * th2 * inv;
    const float qn = 1.0f / sqrtf(qw * qw + qx * qx + qy * qy + qz * qz);
    qw *= qn; qx *= qn; qy *= qn; qz *= qn;
    const float w2 = qw * qw, x2 = qx * qx, y2 = qy * qy, z2 = qz * qz;
    const float wx = qw * qx, wy = qw * qy, wz = qw * qz;
    const float xy = qx * qy, xz = qx * qz, yz = qy * qz;
    R[0] = w2 + x2 - y2 - z2; R[1] = 2.f * (xy - wz);   R[2] = 2.f * (xz + wy);
    R[3] = 2.f * (xy + wz);   R[4] = w2 - x2 + y2 - z2; R[5] = 2.f * (yz - wx);
    R[6] = 2.f * (xz - wy);   R[7] = 2.f * (yz + wx);   R[8] = w2 - x2 - y2 + z2;
    #pragma unroll
    for (int c = 0; c < 3; ++c) Jv[c] = Jl[j * 3 + c];
    if (j >= 1) {
      #pragma unroll
      for (int k = 0; k < 9; ++k)
        pf[(j - 1) * 9 + k] = R[k] - ((k == 0 || k == 4 || k == 8) ? 1.f : 0.f);
    }
  }
  __syncthreads();
  for (int lvl = 0; lvl < 9; ++lvl) {
    if (t < NJ && dep[t] == lvl) {
      if (t == 0) {
        #pragma unroll
        for (int i = 0; i < 3; ++i) {
          Am[i * 4 + 0] = R[i * 3 + 0]; Am[i * 4 + 1] = R[i * 3 + 1];
          Am[i * 4 + 2] = R[i * 3 + 2]; Am[i * 4 + 3] = Jv[i];
        }
      } else {
        const int p = par[t];
        const float tr0 = Jv[0] - Jl[p * 3 + 0];
        const float tr1 = Jv[1] - Jl[p * 3 + 1];
        const float tr2 = Jv[2] - Jl[p * 3 + 2];
        float Pr[12];
        #pragma unroll
        for (int k = 0; k < 12; ++k) Pr[k] = Am[p * 12 + k];
        #pragma unroll
        for (int i = 0; i < 3; ++i) {
          const float r0 = Pr[i*4+0], r1 = Pr[i*4+1], r2 = Pr[i*4+2], r3 = Pr[i*4+3];
          Am[t * 12 + i * 4 + 0] = r0 * R[0] + r1 * R[3] + r2 * R[6];
          Am[t * 12 + i * 4 + 1] = r0 * R[1] + r1 * R[4] + r2 * R[7];
          Am[t * 12 + i * 4 + 2] = r0 * R[2] + r1 * R[5] + r2 * R[8];
          Am[t * 12 + i * 4 + 3] = r0 * tr0 + r1 * tr1 + r2 * tr2 + r3;
        }
      }
    }
    __syncthreads();
  }
  if (t < NJ) {
    float res[12];
    #pragma unroll
    for (int k = 0; k < 12; ++k) res[k] = Am[t * 12 + k];
    #pragma unroll
    for (int i = 0; i < 3; ++i) {
      const float r0 = res[i * 4 + 0], r1 = res[i * 4 + 1], r2 = res[i * 4 + 2];
      Am[t * 12 + i * 4 + 3] = res[i * 4 + 3] - (r0 * Jv[0] + r1 * Jv[1] + r2 * Jv[2]);
    }
  }
  __syncthreads();
  for (int r = 0; r < 207; ++r) {
    const float f = pf[r];
    const float* __restrict__ pr = pd + (size_t)r * 20670;
    for (int e = t; e < NV * 3; e += 256) vs[e] += f * pr[e];
  }
  __syncthreads();
  float jacc[72];
  #pragma unroll
  for (int k = 0; k < 72; ++k) jacc[k] = 0.f;
  for (int v = t; v < NV; v += 256) {
    const float vp0 = vs[3 * v + 0];
    const float vp1 = vs[3 * v + 1];
    const float vp2 = vs[3 * v + 2];
    float tA[12];
    #pragma unroll
    for (int k = 0; k < 12; ++k) tA[k] = 0.f;
    const float* __restrict__ wp = wts + (size_t)v * NJ;
    #pragma unroll
    for (int j = 0; j < NJ; ++j) {
      const float wj = wp[j];
      #pragma unroll
      for (int k = 0; k < 12; ++k) tA[k] += wj * Am[j * 12 + k];
    }
    const float vx = tA[0] * vp0 + tA[1] * vp1 + tA[2]  * vp2 + tA[3];
    const float vy = tA[4] * vp0 + tA[5] * vp1 + tA[6]  * vp2 + tA[7];
    const float vz = tA[8] * vp0 + tA[9] * vp1 + tA[10] * vp2 + tA[11];
    const float* __restrict__ jp = Jr + (size_t)v * NJ;
    #pragma unroll
    for (int jj = 0; jj < NJ; ++jj) {
      const float g = jp[jj];
      jacc[jj * 3 + 0] += g * vx;
      jacc[jj * 3 + 1] += g * vy;
      jacc[jj * 3 + 2] += g * vz;
    }
  }
  #pragma unroll
  for (int k = 0; k < 72; ++k) atomicAdd(&jred[k], jacc[k]);
  __syncthreads();
  if (t < 72) out[(size_t)b * 72 + t] = jred[t];
}

extern "C" void kernel_launch(void* const* d_in, const int* in_sizes, int n_in,
                              void* d_out, int out_size, void* d_ws, size_t ws_size,
                              hipStream_t stream) {
  const float* beta  = (const float*)d_in[0];
  const float* theta = (const float*)d_in[1];
  const float* vt    = (const float*)d_in[2];
  const float* sd    = (const float*)d_in[3];
  const float* pd    = (const float*)d_in[4];
  const float* Jr    = (const float*)d_in[5];
  const float* wts   = (const float*)d_in[6];
  float* out = (float*)d_out;
  (void)in_sizes; (void)n_in; (void)out_size;

  if (ws_size >= TOTAL_WS) {
    char* ws = (char*)d_ws;
    float* P  = (float*)(ws + OFF_P);
    float* D  = (float*)(ws + OFF_D);
    float* KQ = (float*)(ws + OFF_KQ);
    float* W  = (float*)(ws + OFF_W);
    float* JQ = (float*)(ws + OFF_JQ);
    float* qT = (float*)(ws + OFF_Q);
    float* A  = (float*)(ws + OFF_A);
    float* M  = (float*)(ws + OFF_M);   // aliases P (P dead after k_reduce)

    k_dfill<<<dim3((NV + 63) / 64, 10), 256, 0, stream>>>(vt, sd, pd, D);
    k_gemm1<<<dim3(11, 10, NZ), 256, 0, stream>>>(Jr, wts, D, P);
    k_reduce<<<MM, 256, 0, stream>>>(P, KQ, W, JQ);
    k_chain<<<NB, 64, 0, stream>>>(beta, theta, JQ, qT, A);
    k_mgemm<<<dim3(27, 16), 256, 0, stream>>>(qT, KQ, M);
    k_joints<<<NB, 256, 0, stream>>>(M, A, W, out);
  } else {
    k_all<<<NB, 256, 0, stream>>>(beta, theta, vt, sd, pd, Jr, wts, out);
  }
}